// Round 18
// baseline (108.567 us; speedup 1.0000x reference)
//
#include <hip/hip_runtime.h>

#define S 1048576
typedef unsigned short u16;
typedef unsigned int u32;
typedef __attribute__((ext_vector_type(8))) short s8v;   // 8 bf16 (4 VGPRs)
typedef __attribute__((ext_vector_type(4))) float f4v;   // MFMA acc

__device__ __forceinline__ float bf2f(u16 u){
    union { float f; u32 u; } v; v.u = ((u32)u) << 16; return v.f;
}
__device__ __forceinline__ u16 f2bf(float x){
    u32 u = __float_as_uint(x);
    u32 r = (u + 0x7FFFu + ((u >> 16) & 1u)) >> 16;   // RNE
    return (u16)r;
}
// XOR-swizzled LDS index (u16 units): 128-byte rows of 8 16B chunks, chunk ^= row&7
__device__ __forceinline__ int sidx(int r, int c){ return (r<<6) + (((c) ^ (r&7))<<3); }
// async global->LDS, 16B per lane; LDS dest = wave-uniform base + lane*16
__device__ __forceinline__ void gl16(const void* g, void* l){
    __builtin_amdgcn_global_load_lds((const __attribute__((address_space(1))) void*)g,
                                     (__attribute__((address_space(3))) void*)l, 16, 0, 0);
}
// convert 1 chunk (2048 fp32 -> 2048 bf16), chunk u, thread t
__device__ __forceinline__ void xconv1(const float* __restrict__ X, u16* __restrict__ Xh, int u, int t){
    const size_t idx8 = (size_t)u*2048 + (size_t)t*8;
    float4 v0 = *(const float4*)(X+idx8);
    float4 v1 = *(const float4*)(X+idx8+4);
    float xs[8] = {v0.x,v0.y,v0.z,v0.w,v1.x,v1.y,v1.z,v1.w};
    s8v h;
    #pragma unroll
    for (int i = 0; i < 8; ++i) h[i] = (short)f2bf(xs[i]);
    *(s8v*)(Xh+idx8) = h;
}

// blocks [0,768): A_z = 0.5*(G_z - G_z^T) bf16 hi ONLY (64x64 tiles, z=bid>>8)
// blocks [768,2048): X fp32 -> bf16 hi, chunks [0,2731), grid-stride (if conv grid)
__global__ __launch_bounds__(256) void pre_k(const float* __restrict__ G, u16* __restrict__ Abase,
                                             const float* __restrict__ X, u16* __restrict__ Xh){
    __shared__ float Gt[64][65];
    const int bid = blockIdx.x;
    const int t = threadIdx.x;
    if (bid >= 768){
        for (int u = bid - 768; u < 2731; u += 1280) xconv1(X, Xh, u, t);
        return;
    }
    const int bx = bid & 15, by = (bid >> 4) & 15, z = bid >> 8;
    const float* Gz = G + (size_t)z*S;
    u16* Ah = Abase + (size_t)z*2*S;
    const int row = t >> 2, cq = (t & 3) << 4;
    const int r0 = by << 6, c0 = bx << 6;
    #pragma unroll
    for (int g = 0; g < 4; ++g){
        float4 v = *(const float4*)(Gz + (size_t)(c0+row)*1024 + r0 + cq + g*4);
        Gt[row][cq+g*4+0]=v.x; Gt[row][cq+g*4+1]=v.y; Gt[row][cq+g*4+2]=v.z; Gt[row][cq+g*4+3]=v.w;
    }
    __syncthreads();
    #pragma unroll
    for (int g = 0; g < 2; ++g){
        const float* p = Gz + (size_t)(r0+row)*1024 + c0 + cq + g*8;
        float4 v0 = *(const float4*)(p);
        float4 v1 = *(const float4*)(p+4);
        float xs[8] = {v0.x,v0.y,v0.z,v0.w,v1.x,v1.y,v1.z,v1.w};
        s8v sh;
        #pragma unroll
        for (int i = 0; i < 8; ++i){
            float gt = Gt[cq + g*8 + i][row];
            sh[i] = (short)f2bf(0.5f*(xs[i]-gt));
        }
        *(s8v*)(Ah + (size_t)(r0+row)*1024 + c0 + cq + g*8) = sh;
    }
}

// acc = Ah * Bth^T, 1-pass bf16 MFMA. 64x64 tile, BK=64, 4 waves.
// 3 LDS buffers (48KB -> 3 blocks/CU), depth-2 prefetch, counted vmcnt(4), 1 barrier/K-step.
// Degree-4 Paterson-Stockmeyer: p4 = I + A + A^2/2 + Mb*A^2, Mb = A/6 + A^2/24.
// All operands bf16 hi-only (lo contributions are sub-rounding for bf16 outputs).
// MODE 0: C hi = acc.
// MODE 1: C hi = acc (A2')  AND  O2 hi = (1/6)*Bt - (1/24)*acc   (= Mb)
// MODE 2: O2 hi = I + Pa - 0.5*Pa2 - acc  (= E); z==2 also writes E2^T hi
//         via LDS transpose (coalesced s8v stores instead of 2B scatter).
// XFUSE: blocks with blockIdx.x >= 16 convert X chunks [u0,u1), grid-stride.
template<int MODE, bool XFUSE>
__global__ __launch_bounds__(256) void gemm64_k(const u16* __restrict__ Abase, const u16* __restrict__ Btbase,
                                                u16* __restrict__ Cbase,
                                                const u16* __restrict__ Pab, const u16* __restrict__ Pa2b,
                                                u16* __restrict__ O2base, u16* __restrict__ E2t,
                                                const float* __restrict__ X, u16* __restrict__ Xh,
                                                int u0, int u1){
    __shared__ u16 lds[3*8192];   // 48KB; per buf: A 0..4095, B 4096..8191
    const int t = threadIdx.x;
    if (XFUSE && blockIdx.x >= 16){
        const int nb = (int)gridDim.x - 16;
        const int e = ((int)(blockIdx.z*gridDim.y + blockIdx.y))*nb + ((int)blockIdx.x - 16);
        const int E = nb*(int)gridDim.y*(int)gridDim.z;
        for (int u = u0 + e; u < u1; u += E) xconv1(X, Xh, u, t);
        return;
    }
    const int z = blockIdx.z;
    int bx, by;
    if (XFUSE){ bx = blockIdx.x; by = blockIdx.y; }
    else {
        const int lin = (int)blockIdx.x + ((int)blockIdx.y << 4);
        const int sw = (lin & 7)*32 + (lin >> 3);      // bijective on 256
        bx = sw & 15; by = sw >> 4;
    }
    const u16* Ah = Abase  + (size_t)z*2*S;
    const u16* Bh = Btbase + (size_t)z*2*S;
    u16* Ch = Cbase + (size_t)z*2*S;
    const u16* Pah = Pab + (size_t)z*2*S;
    const u16* P2h = Pa2b + (size_t)z*2*S;
    u16* O2h = O2base + (size_t)z*2*S;
    const int brow = by << 6, bcol = bx << 6;
    const int lane = t & 63, w = t >> 6;
    const int wm = (w >> 1) << 5, wn = (w & 1) << 5;
    const int lr = lane & 15, g = lane >> 4;
    int qq[2]; size_t goA[2], goB[2];
    #pragma unroll
    for (int i = 0; i < 2; ++i){
        int q = (((w<<1)+i)<<6) + lane;
        int r = q >> 3, c = lane & 7;
        qq[i] = q << 3;
        goA[i] = (size_t)(brow+r)*1024 + ((c^(r&7))<<3);
        goB[i] = (size_t)(bcol+r)*1024 + ((c^(r&7))<<3);
    }
    auto issue = [&](int kt){
        u16* L = lds + (kt % 3) * 8192;
        const int k0 = kt << 6;
        #pragma unroll
        for (int i = 0; i < 2; ++i){
            gl16(Ah + goA[i] + k0, L + qq[i]);
            gl16(Bh + goB[i] + k0, L + 4096 + qq[i]);
        }
    };
    issue(0); issue(1);
    f4v acc[2][2] = {};
    for (int kt = 0; kt < 16; ++kt){
        if (kt < 15) asm volatile("s_waitcnt vmcnt(4)" ::: "memory");
        else         asm volatile("s_waitcnt vmcnt(0)" ::: "memory");
        __builtin_amdgcn_s_barrier();
        __builtin_amdgcn_sched_barrier(0);
        if (kt < 14) issue(kt + 2);
        const u16* L = lds + (kt % 3) * 8192;
        #pragma unroll
        for (int ks = 0; ks < 2; ++ks){
            const int ch = (ks << 2) + g;
            s8v a_h[2], b_h[2];
            #pragma unroll
            for (int f = 0; f < 2; ++f){
                const int ra = wm+(f<<4)+lr, rb = wn+(f<<4)+lr;
                a_h[f] = *(const s8v*)&L[sidx(ra,ch)];
                b_h[f] = *(const s8v*)&L[4096 + sidx(rb,ch)];
            }
            __builtin_amdgcn_s_setprio(1);
            #pragma unroll
            for (int mf = 0; mf < 2; ++mf)
                #pragma unroll
                for (int nf = 0; nf < 2; ++nf)
                    acc[mf][nf] = __builtin_amdgcn_mfma_f32_16x16x32_bf16(a_h[mf], b_h[nf], acc[mf][nf], 0,0,0);
            __builtin_amdgcn_s_setprio(0);
        }
    }
    const int orr = g << 2;
    u16 hsv[2][2][4];
    #pragma unroll
    for (int mf = 0; mf < 2; ++mf)
        #pragma unroll
        for (int nf = 0; nf < 2; ++nf)
            #pragma unroll
            for (int r = 0; r < 4; ++r){
                const int orow = brow + wm + (mf<<4) + orr + r;
                const int ocol = bcol + wn + (nf<<4) + lr;
                const size_t off = (size_t)orow*1024 + ocol;
                const float av = acc[mf][nf][r];
                if (MODE == 0){
                    Ch[off] = f2bf(av);
                }
                if (MODE == 1){
                    Ch[off] = f2bf(av);                 // A2' = -A^2 (hi)
                    float a = bf2f(Bh[off]);            // A (Bt operand is A, hi)
                    O2h[off] = f2bf((1.0f/6.0f)*a - (1.0f/24.0f)*av);   // Mb
                }
                if (MODE == 2){
                    float a  = bf2f(Pah[off]);          // A (hi)
                    float a2 = bf2f(P2h[off]);          // A2' (hi)
                    float e = a - 0.5f*a2 - av + (orow == ocol ? 1.0f : 0.0f);
                    u16 h = f2bf(e);
                    O2h[off] = h;                       // E hi
                    hsv[mf][nf][r] = h;
                }
            }
    if (MODE == 2 && z == 2){
        // E2^T via LDS transpose: coalesced stores
        u16 (*Tt)[72] = (u16(*)[72])lds;
        __builtin_amdgcn_s_barrier();                   // K-loop LDS reads complete everywhere
        #pragma unroll
        for (int mf = 0; mf < 2; ++mf)
            #pragma unroll
            for (int nf = 0; nf < 2; ++nf)
                #pragma unroll
                for (int r = 0; r < 4; ++r){
                    const int lrow = wm + (mf<<4) + orr + r;   // orow - brow
                    const int lcol = wn + (nf<<4) + lr;        // ocol - bcol
                    Tt[lcol][lrow] = hsv[mf][nf][r];
                }
        __builtin_amdgcn_s_barrier();
        const int rr = t >> 2, cc = (t & 3) << 1;
        #pragma unroll
        for (int i = 0; i < 2; ++i){
            s8v v = *(const s8v*)&Tt[rr][(cc+i)<<3];
            *(s8v*)&E2t[(size_t)(bcol+rr)*1024 + brow + ((cc+i)<<3)] = v;
        }
    }
}

// Y[16384,1024] = Xh * Rh.  256x256 tile, BK=64, 8 waves (wave tile 128x64), 1-pass,
// DMA staging, dbuf (128KB), 1 syncthreads/K-step, bijective XCD swizzle.
// (R8/R11/R14/R17-proven best structure for the big GEMM: 41.3 us.)
__global__ __launch_bounds__(512) void gemm_big3(const u16* __restrict__ Xh, const u16* __restrict__ Rth,
                                                 float* __restrict__ Y){
    __shared__ u16 lds[2][32768];  // per buf: X 0..16383 (256x64), B 16384..32767 (256x64)
    const int bid = blockIdx.x;
    const int swz = (bid & 7)*32 + (bid >> 3);     // 256 blocks, 8 XCDs, bijective
    const int by = swz >> 2, bx = swz & 3;
    const int brow = by << 8, bcol = bx << 8;
    const int t = threadIdx.x;
    const int lane = t & 63, w = t >> 6;
    const int wm = (w >> 2) << 7, wn = (w & 3) << 6;   // 2x4 wave grid, wave tile 128x64
    const int lr = lane & 15, g = lane >> 4;
    int xq[4]; size_t gx[4], gb[4];
    #pragma unroll
    for (int i = 0; i < 4; ++i){
        int q = (((w<<2)+i)<<6) + lane;   // 0..2047 chunks per region
        int r = q >> 3, c = lane & 7;
        xq[i] = q << 3;
        gx[i] = (size_t)(brow+r)*1024 + ((c^(r&7))<<3);
        gb[i] = (size_t)(bcol+r)*1024 + ((c^(r&7))<<3);
    }
    f4v acc[8][4] = {};
    {
        u16* L = lds[0];
        #pragma unroll
        for (int i = 0; i < 4; ++i){
            gl16(Xh  + gx[i], L + xq[i]);
            gl16(Rth + gb[i], L + 16384 + xq[i]);
        }
    }
    int cur = 0;
    for (int kt = 0; kt < 16; ++kt){
        __syncthreads();
        if (kt < 15){
            u16* L = lds[cur^1];
            const int k0 = (kt+1) << 6;
            #pragma unroll
            for (int i = 0; i < 4; ++i){
                gl16(Xh  + gx[i] + k0, L + xq[i]);
                gl16(Rth + gb[i] + k0, L + 16384 + xq[i]);
            }
        }
        const u16* L = lds[cur];
        #pragma unroll
        for (int ks = 0; ks < 2; ++ks){
            const int ch = (ks << 2) + g;
            s8v bh[4];
            #pragma unroll
            for (int nf = 0; nf < 4; ++nf){
                const int rb = wn+(nf<<4)+lr;
                bh[nf] = *(const s8v*)&L[16384 + sidx(rb,ch)];
            }
            __builtin_amdgcn_s_setprio(1);
            #pragma unroll
            for (int mf = 0; mf < 8; ++mf){
                const int ra = wm+(mf<<4)+lr;
                s8v a = *(const s8v*)&L[sidx(ra,ch)];
                #pragma unroll
                for (int nf = 0; nf < 4; ++nf)
                    acc[mf][nf] = __builtin_amdgcn_mfma_f32_16x16x32_bf16(a, bh[nf], acc[mf][nf], 0,0,0);
            }
            __builtin_amdgcn_s_setprio(0);
        }
        cur ^= 1;
    }
    const int orr = g << 2;
    #pragma unroll
    for (int mf = 0; mf < 8; ++mf)
        #pragma unroll
        for (int nf = 0; nf < 4; ++nf)
            #pragma unroll
            for (int r = 0; r < 4; ++r){
                int orow = brow + wm + (mf<<4) + orr + r;
                int ocol = bcol + wn + (nf<<4) + lr;
                Y[(size_t)orow*1024 + ocol] = acc[mf][nf][r];
            }
}

// Fallback (ws too small for Xh): direct-fp32 X, reg-staged conversion (R13 structure).
__global__ __launch_bounds__(512) void gemm_big3x(const float* __restrict__ X, const u16* __restrict__ Rth,
                                                  float* __restrict__ Y){
    __shared__ u16 lds[2*32768];
    const int bid = blockIdx.x;
    const int swz = (bid & 7)*32 + (bid >> 3);
    const int by = swz >> 2, bx = swz & 3;
    const int brow = by << 8, bcol = bx << 8;
    const int t = threadIdx.x;
    const int lane = t & 63, w = t >> 6;
    const int wm = (w >> 2) << 7, wn = (w & 3) << 6;
    const int lr = lane & 15, g = lane >> 4;
    int bq[4]; size_t gb[4];
    #pragma unroll
    for (int i = 0; i < 4; ++i){
        int q = (((w<<2)+i)<<6) + lane;
        int r = q >> 3, c = lane & 7;
        bq[i] = q << 3;
        gb[i] = (size_t)(bcol+r)*1024 + ((c^(r&7))<<3);
    }
    int xrow[4], xc[4];
    #pragma unroll
    for (int i = 0; i < 4; ++i){ int q = (i<<9) + t; xrow[i] = q >> 3; xc[i] = q & 7; }
    auto issueB = [&](int kt){
        u16* L = lds + ((kt & 1) << 15) + 16384;
        const int k0 = kt << 6;
        #pragma unroll
        for (int i = 0; i < 4; ++i) gl16(Rth + gb[i] + k0, L + bq[i]);
    };
    float4 xf[4][2];
    auto loadX = [&](int kt){
        const int k0 = kt << 6;
        #pragma unroll
        for (int i = 0; i < 4; ++i){
            const float* p = X + (size_t)(brow+xrow[i])*1024 + k0 + (xc[i]<<3);
            xf[i][0] = *(const float4*)(p);
            xf[i][1] = *(const float4*)(p+4);
        }
    };
    auto writeX = [&](int kt){
        u16* L = lds + ((kt & 1) << 15);
        #pragma unroll
        for (int i = 0; i < 4; ++i){
            float xs[8] = {xf[i][0].x, xf[i][0].y, xf[i][0].z, xf[i][0].w,
                           xf[i][1].x, xf[i][1].y, xf[i][1].z, xf[i][1].w};
            s8v h;
            #pragma unroll
            for (int j = 0; j < 8; ++j) h[j] = (short)f2bf(xs[j]);
            *(s8v*)&L[sidx(xrow[i], xc[i])] = h;
        }
    };
    f4v acc[8][4] = {};
    loadX(0); issueB(0); writeX(0);
    for (int kt = 0; kt < 16; ++kt){
        __syncthreads();
        if (kt < 15){ loadX(kt + 1); issueB(kt + 1); }
        const u16* L = lds + ((kt & 1) << 15);
        #pragma unroll
        for (int ks = 0; ks < 2; ++ks){
            const int ch = (ks << 2) + g;
            s8v bh[4];
            #pragma unroll
            for (int nf = 0; nf < 4; ++nf){
                const int rb = wn+(nf<<4)+lr;
                bh[nf] = *(const s8v*)&L[16384 + sidx(rb,ch)];
            }
            __builtin_amdgcn_s_setprio(1);
            #pragma unroll
            for (int mf = 0; mf < 8; ++mf){
                const int ra = wm+(mf<<4)+lr;
                s8v a = *(const s8v*)&L[sidx(ra,ch)];
                #pragma unroll
                for (int nf = 0; nf < 4; ++nf)
                    acc[mf][nf] = __builtin_amdgcn_mfma_f32_16x16x32_bf16(a, bh[nf], acc[mf][nf], 0,0,0);
            }
            __builtin_amdgcn_s_setprio(0);
        }
        if (kt < 15) writeX(kt + 1);
    }
    const int orr = g << 2;
    #pragma unroll
    for (int mf = 0; mf < 8; ++mf)
        #pragma unroll
        for (int nf = 0; nf < 4; ++nf)
            #pragma unroll
            for (int r = 0; r < 4; ++r){
                int orow = brow + wm + (mf<<4) + orr + r;
                int ocol = bcol + wn + (nf<<4) + lr;
                Y[(size_t)orow*1024 + ocol] = acc[mf][nf][r];
            }
}

extern "C" void kernel_launch(void* const* d_in, const int* in_sizes, int n_in,
                              void* d_out, int out_size, void* d_ws, size_t ws_size,
                              hipStream_t stream) {
    const float* X = (const float*)d_in[0];   // [16384,1024] fp32
    const float* G = (const float*)d_in[1];   // [3,1024,1024] fp32
    float* out = (float*)d_out;
    u16* ob = (u16*)d_out;                    // 16 pair-slots of 2*S u16 each
    auto slot = [&](int i){ return ob + (size_t)i*2*S; };
    u16* RT = (u16*)d_ws;                     // R^T hi (4 MB reserved)
    u16* Xh = RT + (size_t)2*S;               // X hi bf16 (32 MB)
    const bool ws_ok = ws_size >= (size_t)36*S;   // bytes: RT(4MB) + Xh(32MB)

    dim3 b(256);
    // slots: A:0-2(hi)  A2':3-5(hi)  Mb:6-8(hi)  E:9-11(hi)  M1:12(hi)  E2t:15(hi)
    pre_k<<<dim3(ws_ok ? 2048 : 768), b, 0, stream>>>(G, slot(0), X, Xh);             // A hi (+X conv 1/3)
    gemm64_k<1,false><<<dim3(16,16,3), b, 0, stream>>>(slot(0), slot(0), slot(3),
                                                       slot(0), slot(0), slot(6), slot(15),
                                                       X, Xh, 0, 0);                  // A2' ; Mb
    gemm64_k<2,false><<<dim3(16,16,3), b, 0, stream>>>(slot(6), slot(3), slot(14),
                                                       slot(0), slot(3), slot(9), slot(15),
                                                       X, Xh, 0, 0);                  // E (+E2^T)
    if (ws_ok){
        gemm64_k<0,true><<<dim3(64,16,1), b, 0, stream>>>(slot(15), slot(10), slot(12),
                                                          slot(0), slot(0), slot(12), slot(15),
                                                          X, Xh, 2731, 5462);         // M1 (+X conv 1/3)
        gemm64_k<0,true><<<dim3(64,16,1), b, 0, stream>>>(slot(12), slot(9), RT,
                                                          slot(0), slot(0), RT, slot(15),
                                                          X, Xh, 5462, 8192);         // RT (+X conv 1/3)
        gemm_big3<<<dim3(256), dim3(512), 0, stream>>>(Xh, RT, out);                  // Y = X*R
    } else {
        gemm64_k<0,false><<<dim3(16,16,1), b, 0, stream>>>(slot(15), slot(10), slot(12),
                                                           slot(0), slot(0), slot(12), slot(15),
                                                           X, Xh, 0, 0);              // M1
        gemm64_k<0,false><<<dim3(16,16,1), b, 0, stream>>>(slot(12), slot(9), RT,
                                                           slot(0), slot(0), RT, slot(15),
                                                           X, Xh, 0, 0);              // RT
        gemm_big3x<<<dim3(256), dim3(512), 0, stream>>>(X, RT, out);
    }
}

// Round 19
// 103.399 us; speedup vs baseline: 1.0500x; 1.0500x over previous
//
#include <hip/hip_runtime.h>

#define S 1048576
typedef unsigned short u16;
typedef unsigned int u32;
typedef __attribute__((ext_vector_type(8))) short s8v;   // 8 bf16 (4 VGPRs)
typedef __attribute__((ext_vector_type(4))) float f4v;   // MFMA acc

__device__ __forceinline__ float bf2f(u16 u){
    union { float f; u32 u; } v; v.u = ((u32)u) << 16; return v.f;
}
__device__ __forceinline__ u16 f2bf(float x){
    u32 u = __float_as_uint(x);
    u32 r = (u + 0x7FFFu + ((u >> 16) & 1u)) >> 16;   // RNE
    return (u16)r;
}
// XOR-swizzled LDS index (u16 units): 128-byte rows of 8 16B chunks, chunk ^= row&7
__device__ __forceinline__ int sidx(int r, int c){ return (r<<6) + (((c) ^ (r&7))<<3); }
// async global->LDS, 16B per lane; LDS dest = wave-uniform base + lane*16
__device__ __forceinline__ void gl16(const void* g, void* l){
    __builtin_amdgcn_global_load_lds((const __attribute__((address_space(1))) void*)g,
                                     (__attribute__((address_space(3))) void*)l, 16, 0, 0);
}
// convert N contiguous chunks (2048 fp32 -> 2048 bf16 each); all loads issued before stores
template<int N>
__device__ __forceinline__ void xconvN(const float* __restrict__ X, u16* __restrict__ Xh, int u0, int t){
    float4 va[N], vb[N];
    #pragma unroll
    for (int i = 0; i < N; ++i){
        const float* p = X + (size_t)(u0+i)*2048 + (size_t)t*8;
        va[i] = *(const float4*)p;
        vb[i] = *(const float4*)(p+4);
    }
    #pragma unroll
    for (int i = 0; i < N; ++i){
        float xs[8] = {va[i].x,va[i].y,va[i].z,va[i].w,vb[i].x,vb[i].y,vb[i].z,vb[i].w};
        s8v h;
        #pragma unroll
        for (int j = 0; j < 8; ++j) h[j] = (short)f2bf(xs[j]);
        *(s8v*)(Xh + (size_t)(u0+i)*2048 + (size_t)t*8) = h;
    }
}

// blocks [0,768): A_z = 0.5*(G_z - G_z^T) bf16 hi ONLY (64x64 tiles, z=bid>>8);
//                 first 512 of them also convert 1 X-chunk each (chunks 7680..8191).
// blocks [768,2048): 6 contiguous X chunks each (chunks 0..7679), batched loads.
__global__ __launch_bounds__(256) void pre_k(const float* __restrict__ G, u16* __restrict__ Abase,
                                             const float* __restrict__ X, u16* __restrict__ Xh){
    __shared__ float Gt[64][65];
    const int bid = blockIdx.x;
    const int t = threadIdx.x;
    if (bid >= 768){
        xconvN<6>(X, Xh, (bid - 768)*6, t);
        return;
    }
    const int bx = bid & 15, by = (bid >> 4) & 15, z = bid >> 8;
    const float* Gz = G + (size_t)z*S;
    u16* Ah = Abase + (size_t)z*2*S;
    const int row = t >> 2, cq = (t & 3) << 4;
    const int r0 = by << 6, c0 = bx << 6;
    #pragma unroll
    for (int g = 0; g < 4; ++g){
        float4 v = *(const float4*)(Gz + (size_t)(c0+row)*1024 + r0 + cq + g*4);
        Gt[row][cq+g*4+0]=v.x; Gt[row][cq+g*4+1]=v.y; Gt[row][cq+g*4+2]=v.z; Gt[row][cq+g*4+3]=v.w;
    }
    __syncthreads();
    #pragma unroll
    for (int g = 0; g < 2; ++g){
        const float* p = Gz + (size_t)(r0+row)*1024 + c0 + cq + g*8;
        float4 v0 = *(const float4*)(p);
        float4 v1 = *(const float4*)(p+4);
        float xs[8] = {v0.x,v0.y,v0.z,v0.w,v1.x,v1.y,v1.z,v1.w};
        s8v sh;
        #pragma unroll
        for (int i = 0; i < 8; ++i){
            float gt = Gt[cq + g*8 + i][row];
            sh[i] = (short)f2bf(0.5f*(xs[i]-gt));
        }
        *(s8v*)(Ah + (size_t)(r0+row)*1024 + c0 + cq + g*8) = sh;
    }
    if (gridDim.x > 768 && bid < 512)
        xconvN<1>(X, Xh, 7680 + bid, t);
}

// acc = Ah * Bth^T, 1-pass bf16 MFMA. 64x64 tile, BK=64, 4 waves.
// 3 LDS buffers (48KB -> 3 blocks/CU), depth-2 prefetch, counted vmcnt(4), 1 barrier/K-step.
// Degree-4 Paterson-Stockmeyer: p4 = I + A + A^2/2 + Mb*A^2, Mb = A/6 + A^2/24.
// All operands bf16 hi-only (lo contributions are sub-rounding for bf16 outputs).
// MODE 0: C hi = acc.
// MODE 1: C hi = acc (A2')  AND  O2 hi = (1/6)*Bt - (1/24)*acc   (= Mb)
// MODE 2: O2 hi = I + Pa - 0.5*Pa2 - acc  (= E); z==2 also writes E2^T hi
//         via LDS transpose (coalesced s8v stores instead of 2B scatter).
template<int MODE>
__global__ __launch_bounds__(256) void gemm64_k(const u16* __restrict__ Abase, const u16* __restrict__ Btbase,
                                                u16* __restrict__ Cbase,
                                                const u16* __restrict__ Pab, const u16* __restrict__ Pa2b,
                                                u16* __restrict__ O2base, u16* __restrict__ E2t){
    __shared__ u16 lds[3*8192];   // 48KB; per buf: A 0..4095, B 4096..8191
    const int t = threadIdx.x;
    const int z = blockIdx.z;
    const int lin = (int)blockIdx.x + ((int)blockIdx.y << 4);
    const int sw = (lin & 7)*32 + (lin >> 3);      // bijective on 256
    const int bx = sw & 15, by = sw >> 4;
    const u16* Ah = Abase  + (size_t)z*2*S;
    const u16* Bh = Btbase + (size_t)z*2*S;
    u16* Ch = Cbase + (size_t)z*2*S;
    const u16* Pah = Pab + (size_t)z*2*S;
    const u16* P2h = Pa2b + (size_t)z*2*S;
    u16* O2h = O2base + (size_t)z*2*S;
    const int brow = by << 6, bcol = bx << 6;
    const int lane = t & 63, w = t >> 6;
    const int wm = (w >> 1) << 5, wn = (w & 1) << 5;
    const int lr = lane & 15, g = lane >> 4;
    int qq[2]; size_t goA[2], goB[2];
    #pragma unroll
    for (int i = 0; i < 2; ++i){
        int q = (((w<<1)+i)<<6) + lane;
        int r = q >> 3, c = lane & 7;
        qq[i] = q << 3;
        goA[i] = (size_t)(brow+r)*1024 + ((c^(r&7))<<3);
        goB[i] = (size_t)(bcol+r)*1024 + ((c^(r&7))<<3);
    }
    auto issue = [&](int kt){
        u16* L = lds + (kt % 3) * 8192;
        const int k0 = kt << 6;
        #pragma unroll
        for (int i = 0; i < 2; ++i){
            gl16(Ah + goA[i] + k0, L + qq[i]);
            gl16(Bh + goB[i] + k0, L + 4096 + qq[i]);
        }
    };
    issue(0); issue(1);
    f4v acc[2][2] = {};
    for (int kt = 0; kt < 16; ++kt){
        if (kt < 15) asm volatile("s_waitcnt vmcnt(4)" ::: "memory");
        else         asm volatile("s_waitcnt vmcnt(0)" ::: "memory");
        __builtin_amdgcn_s_barrier();
        __builtin_amdgcn_sched_barrier(0);
        if (kt < 14) issue(kt + 2);
        const u16* L = lds + (kt % 3) * 8192;
        #pragma unroll
        for (int ks = 0; ks < 2; ++ks){
            const int ch = (ks << 2) + g;
            s8v a_h[2], b_h[2];
            #pragma unroll
            for (int f = 0; f < 2; ++f){
                const int ra = wm+(f<<4)+lr, rb = wn+(f<<4)+lr;
                a_h[f] = *(const s8v*)&L[sidx(ra,ch)];
                b_h[f] = *(const s8v*)&L[4096 + sidx(rb,ch)];
            }
            __builtin_amdgcn_s_setprio(1);
            #pragma unroll
            for (int mf = 0; mf < 2; ++mf)
                #pragma unroll
                for (int nf = 0; nf < 2; ++nf)
                    acc[mf][nf] = __builtin_amdgcn_mfma_f32_16x16x32_bf16(a_h[mf], b_h[nf], acc[mf][nf], 0,0,0);
            __builtin_amdgcn_s_setprio(0);
        }
    }
    const int orr = g << 2;
    u16 hsv[2][2][4];
    #pragma unroll
    for (int mf = 0; mf < 2; ++mf)
        #pragma unroll
        for (int nf = 0; nf < 2; ++nf)
            #pragma unroll
            for (int r = 0; r < 4; ++r){
                const int orow = brow + wm + (mf<<4) + orr + r;
                const int ocol = bcol + wn + (nf<<4) + lr;
                const size_t off = (size_t)orow*1024 + ocol;
                const float av = acc[mf][nf][r];
                if (MODE == 0){
                    Ch[off] = f2bf(av);
                }
                if (MODE == 1){
                    Ch[off] = f2bf(av);                 // A2' = -A^2 (hi)
                    float a = bf2f(Bh[off]);            // A (Bt operand is A, hi)
                    O2h[off] = f2bf((1.0f/6.0f)*a - (1.0f/24.0f)*av);   // Mb
                }
                if (MODE == 2){
                    float a  = bf2f(Pah[off]);          // A (hi)
                    float a2 = bf2f(P2h[off]);          // A2' (hi)
                    float e = a - 0.5f*a2 - av + (orow == ocol ? 1.0f : 0.0f);
                    u16 h = f2bf(e);
                    O2h[off] = h;                       // E hi
                    hsv[mf][nf][r] = h;
                }
            }
    if (MODE == 2 && z == 2){
        // E2^T via LDS transpose: coalesced stores
        u16 (*Tt)[72] = (u16(*)[72])lds;
        __builtin_amdgcn_s_barrier();                   // K-loop LDS reads complete everywhere
        #pragma unroll
        for (int mf = 0; mf < 2; ++mf)
            #pragma unroll
            for (int nf = 0; nf < 2; ++nf)
                #pragma unroll
                for (int r = 0; r < 4; ++r){
                    const int lrow = wm + (mf<<4) + orr + r;   // orow - brow
                    const int lcol = wn + (nf<<4) + lr;        // ocol - bcol
                    Tt[lcol][lrow] = hsv[mf][nf][r];
                }
        __builtin_amdgcn_s_barrier();
        const int rr = t >> 2, cc = (t & 3) << 1;
        #pragma unroll
        for (int i = 0; i < 2; ++i){
            s8v v = *(const s8v*)&Tt[rr][(cc+i)<<3];
            *(s8v*)&E2t[(size_t)(bcol+rr)*1024 + brow + ((cc+i)<<3)] = v;
        }
    }
}

// Y[16384,1024] = Xh * Rh.  256x256 tile, BK=64, 8 waves (wave tile 128x64), 1-pass,
// DMA staging, dbuf (128KB), 1 syncthreads/K-step, bijective XCD swizzle.
// (R8/R11/R14/R17-proven best structure for the big GEMM: 41.3 us.)
__global__ __launch_bounds__(512) void gemm_big3(const u16* __restrict__ Xh, const u16* __restrict__ Rth,
                                                 float* __restrict__ Y){
    __shared__ u16 lds[2][32768];  // per buf: X 0..16383 (256x64), B 16384..32767 (256x64)
    const int bid = blockIdx.x;
    const int swz = (bid & 7)*32 + (bid >> 3);     // 256 blocks, 8 XCDs, bijective
    const int by = swz >> 2, bx = swz & 3;
    const int brow = by << 8, bcol = bx << 8;
    const int t = threadIdx.x;
    const int lane = t & 63, w = t >> 6;
    const int wm = (w >> 2) << 7, wn = (w & 3) << 6;   // 2x4 wave grid, wave tile 128x64
    const int lr = lane & 15, g = lane >> 4;
    int xq[4]; size_t gx[4], gb[4];
    #pragma unroll
    for (int i = 0; i < 4; ++i){
        int q = (((w<<2)+i)<<6) + lane;   // 0..2047 chunks per region
        int r = q >> 3, c = lane & 7;
        xq[i] = q << 3;
        gx[i] = (size_t)(brow+r)*1024 + ((c^(r&7))<<3);
        gb[i] = (size_t)(bcol+r)*1024 + ((c^(r&7))<<3);
    }
    f4v acc[8][4] = {};
    {
        u16* L = lds[0];
        #pragma unroll
        for (int i = 0; i < 4; ++i){
            gl16(Xh  + gx[i], L + xq[i]);
            gl16(Rth + gb[i], L + 16384 + xq[i]);
        }
    }
    int cur = 0;
    for (int kt = 0; kt < 16; ++kt){
        __syncthreads();
        if (kt < 15){
            u16* L = lds[cur^1];
            const int k0 = (kt+1) << 6;
            #pragma unroll
            for (int i = 0; i < 4; ++i){
                gl16(Xh  + gx[i] + k0, L + xq[i]);
                gl16(Rth + gb[i] + k0, L + 16384 + xq[i]);
            }
        }
        const u16* L = lds[cur];
        #pragma unroll
        for (int ks = 0; ks < 2; ++ks){
            const int ch = (ks << 2) + g;
            s8v bh[4];
            #pragma unroll
            for (int nf = 0; nf < 4; ++nf){
                const int rb = wn+(nf<<4)+lr;
                bh[nf] = *(const s8v*)&L[16384 + sidx(rb,ch)];
            }
            __builtin_amdgcn_s_setprio(1);
            #pragma unroll
            for (int mf = 0; mf < 8; ++mf){
                const int ra = wm+(mf<<4)+lr;
                s8v a = *(const s8v*)&L[sidx(ra,ch)];
                #pragma unroll
                for (int nf = 0; nf < 4; ++nf)
                    acc[mf][nf] = __builtin_amdgcn_mfma_f32_16x16x32_bf16(a, bh[nf], acc[mf][nf], 0,0,0);
            }
            __builtin_amdgcn_s_setprio(0);
        }
        cur ^= 1;
    }
    const int orr = g << 2;
    #pragma unroll
    for (int mf = 0; mf < 8; ++mf)
        #pragma unroll
        for (int nf = 0; nf < 4; ++nf)
            #pragma unroll
            for (int r = 0; r < 4; ++r){
                int orow = brow + wm + (mf<<4) + orr + r;
                int ocol = bcol + wn + (nf<<4) + lr;
                Y[(size_t)orow*1024 + ocol] = acc[mf][nf][r];
            }
}

// Fallback (ws too small for Xh): direct-fp32 X, reg-staged conversion (R13 structure).
__global__ __launch_bounds__(512) void gemm_big3x(const float* __restrict__ X, const u16* __restrict__ Rth,
                                                  float* __restrict__ Y){
    __shared__ u16 lds[2*32768];
    const int bid = blockIdx.x;
    const int swz = (bid & 7)*32 + (bid >> 3);
    const int by = swz >> 2, bx = swz & 3;
    const int brow = by << 8, bcol = bx << 8;
    const int t = threadIdx.x;
    const int lane = t & 63, w = t >> 6;
    const int wm = (w >> 2) << 7, wn = (w & 3) << 6;
    const int lr = lane & 15, g = lane >> 4;
    int bq[4]; size_t gb[4];
    #pragma unroll
    for (int i = 0; i < 4; ++i){
        int q = (((w<<2)+i)<<6) + lane;
        int r = q >> 3, c = lane & 7;
        bq[i] = q << 3;
        gb[i] = (size_t)(bcol+r)*1024 + ((c^(r&7))<<3);
    }
    int xrow[4], xc[4];
    #pragma unroll
    for (int i = 0; i < 4; ++i){ int q = (i<<9) + t; xrow[i] = q >> 3; xc[i] = q & 7; }
    auto issueB = [&](int kt){
        u16* L = lds + ((kt & 1) << 15) + 16384;
        const int k0 = kt << 6;
        #pragma unroll
        for (int i = 0; i < 4; ++i) gl16(Rth + gb[i] + k0, L + bq[i]);
    };
    float4 xf[4][2];
    auto loadX = [&](int kt){
        const int k0 = kt << 6;
        #pragma unroll
        for (int i = 0; i < 4; ++i){
            const float* p = X + (size_t)(brow+xrow[i])*1024 + k0 + (xc[i]<<3);
            xf[i][0] = *(const float4*)(p);
            xf[i][1] = *(const float4*)(p+4);
        }
    };
    auto writeX = [&](int kt){
        u16* L = lds + ((kt & 1) << 15);
        #pragma unroll
        for (int i = 0; i < 4; ++i){
            float xs[8] = {xf[i][0].x, xf[i][0].y, xf[i][0].z, xf[i][0].w,
                           xf[i][1].x, xf[i][1].y, xf[i][1].z, xf[i][1].w};
            s8v h;
            #pragma unroll
            for (int j = 0; j < 8; ++j) h[j] = (short)f2bf(xs[j]);
            *(s8v*)&L[sidx(xrow[i], xc[i])] = h;
        }
    };
    f4v acc[8][4] = {};
    loadX(0); issueB(0); writeX(0);
    for (int kt = 0; kt < 16; ++kt){
        __syncthreads();
        if (kt < 15){ loadX(kt + 1); issueB(kt + 1); }
        const u16* L = lds + ((kt & 1) << 15);
        #pragma unroll
        for (int ks = 0; ks < 2; ++ks){
            const int ch = (ks << 2) + g;
            s8v bh[4];
            #pragma unroll
            for (int nf = 0; nf < 4; ++nf){
                const int rb = wn+(nf<<4)+lr;
                bh[nf] = *(const s8v*)&L[16384 + sidx(rb,ch)];
            }
            __builtin_amdgcn_s_setprio(1);
            #pragma unroll
            for (int mf = 0; mf < 8; ++mf){
                const int ra = wm+(mf<<4)+lr;
                s8v a = *(const s8v*)&L[sidx(ra,ch)];
                #pragma unroll
                for (int nf = 0; nf < 4; ++nf)
                    acc[mf][nf] = __builtin_amdgcn_mfma_f32_16x16x32_bf16(a, bh[nf], acc[mf][nf], 0,0,0);
            }
            __builtin_amdgcn_s_setprio(0);
        }
        if (kt < 15) writeX(kt + 1);
    }
    const int orr = g << 2;
    #pragma unroll
    for (int mf = 0; mf < 8; ++mf)
        #pragma unroll
        for (int nf = 0; nf < 4; ++nf)
            #pragma unroll
            for (int r = 0; r < 4; ++r){
                int orow = brow + wm + (mf<<4) + orr + r;
                int ocol = bcol + wn + (nf<<4) + lr;
                Y[(size_t)orow*1024 + ocol] = acc[mf][nf][r];
            }
}

extern "C" void kernel_launch(void* const* d_in, const int* in_sizes, int n_in,
                              void* d_out, int out_size, void* d_ws, size_t ws_size,
                              hipStream_t stream) {
    const float* X = (const float*)d_in[0];   // [16384,1024] fp32
    const float* G = (const float*)d_in[1];   // [3,1024,1024] fp32
    float* out = (float*)d_out;
    u16* ob = (u16*)d_out;                    // 16 pair-slots of 2*S u16 each
    auto slot = [&](int i){ return ob + (size_t)i*2*S; };
    u16* RT = (u16*)d_ws;                     // R^T hi (4 MB reserved)
    u16* Xh = RT + (size_t)2*S;               // X hi bf16 (32 MB)
    const bool ws_ok = ws_size >= (size_t)36*S;   // bytes: RT(4MB) + Xh(32MB)

    dim3 b(256);
    // slots: A:0-2(hi)  A2':3-5(hi)  Mb:6-8(hi)  E:9-11(hi)  M1:12(hi)  E2t:15(hi)
    pre_k<<<dim3(ws_ok ? 2048 : 768), b, 0, stream>>>(G, slot(0), X, Xh);             // A hi (+full X conv)
    gemm64_k<1><<<dim3(16,16,3), b, 0, stream>>>(slot(0), slot(0), slot(3),
                                                 slot(0), slot(0), slot(6), slot(15));// A2' ; Mb
    gemm64_k<2><<<dim3(16,16,3), b, 0, stream>>>(slot(6), slot(3), slot(14),
                                                 slot(0), slot(3), slot(9), slot(15));// E (+E2^T)
    gemm64_k<0><<<dim3(16,16,1), b, 0, stream>>>(slot(15), slot(10), slot(12),
                                                 slot(0), slot(0), slot(12), slot(15));// M1 = E2^T*E1^T
    gemm64_k<0><<<dim3(16,16,1), b, 0, stream>>>(slot(12), slot(9), RT,
                                                 slot(0), slot(0), RT, slot(15));     // RT = M1*E0^T
    if (ws_ok)
        gemm_big3<<<dim3(256), dim3(512), 0, stream>>>(Xh, RT, out);                  // Y = X*R
    else
        gemm_big3x<<<dim3(256), dim3(512), 0, stream>>>(X, RT, out);
}